// Round 4
// baseline (303.068 us; speedup 1.0000x reference)
//
#include <hip/hip_runtime.h>

typedef unsigned short u16;
typedef unsigned int u32;
typedef unsigned long long u64;
typedef __attribute__((ext_vector_type(8))) short short8;
typedef __attribute__((ext_vector_type(4))) float f32x4;

#define B_ 2
#define T_ 2048
#define H_ 16
#define DK_ 64
#define QSCALE 0.18033688011112042f  // 0.125 * log2(e)

__device__ __forceinline__ u16 f2bf(float f){
  unsigned u = __float_as_uint(f);
  return (u16)((u + 0x7fffu + ((u >> 16) & 1u)) >> 16);
}

__device__ __forceinline__ u32 cvtpk(float lo, float hi){
  u32 r;
  asm("v_cvt_pk_bf16_f32 %0, %1, %2" : "=v"(r) : "v"(lo), "v"(hi));
  return r;
}

#if defined(__has_builtin)
#if __has_builtin(__builtin_amdgcn_global_load_lds)
#define HAS_GLLDS 1
#endif
#endif
#define EXP2(x) __builtin_exp2f(x)

#ifdef HAS_GLLDS
__device__ __forceinline__ void gl_lds16(const u16* g, u16* l){
  __builtin_amdgcn_global_load_lds(
      (__attribute__((address_space(1))) void*)(void*)g,
      (__attribute__((address_space(3))) void*)(void*)l, 16, 0, 0);
}
#endif

// ---------------- fused fp32 -> bf16 convert (x + 4 weights) ----------------
__global__ __launch_bounds__(256) void conv_all(
    const float* __restrict__ x, const float* __restrict__ wq, const float* __restrict__ wk,
    const float* __restrict__ wv, const float* __restrict__ wo,
    u16* __restrict__ xb, u16* __restrict__ wqb, u16* __restrict__ wkb,
    u16* __restrict__ wvb, u16* __restrict__ wob)
{
  int gid = blockIdx.x * 256 + threadIdx.x;
  const float* src; u16* dst; int off;
  if (gid < 1048576){ src = x; dst = xb; off = gid; }
  else {
    int t = gid - 1048576; int s = t >> 18; off = t & 262143;
    src = (s==0)?wq:((s==1)?wk:((s==2)?wv:wo));
    dst = (s==0)?wqb:((s==1)?wkb:((s==2)?wvb:wob));
  }
  float4 v = ((const float4*)src)[off];
  u64 r = (u64)f2bf(v.x) | ((u64)f2bf(v.y)<<16) | ((u64)f2bf(v.z)<<32) | ((u64)f2bf(v.w)<<48);
  ((u64*)dst)[off] = r;
}

// ---------------- GEMM: C[M,1024] = A[M,1024]*W^T + bias, 2-phase dbuf ----------------
// QKV=1: fused Q/K/V (grid.x=24); Q scaled by QSCALE. QKV=0: fp32 out.
template<int QKV>
__global__ __launch_bounds__(256, 3) void gemm_k3(
    const u16* __restrict__ A,
    const u16* __restrict__ W0, const u16* __restrict__ W1, const u16* __restrict__ W2,
    const float* __restrict__ b0, const float* __restrict__ b1, const float* __restrict__ b2,
    void* __restrict__ o0, void* __restrict__ o1, void* __restrict__ o2)
{
  __shared__ u16 As[2][128*32];
  __shared__ u16 Bs[2][128*32];
  const int tid = threadIdx.x;
  const int sel = QKV ? (blockIdx.x >> 3) : 0;
  const int n0 = (blockIdx.x & 7) * 128;
  const int m0 = blockIdx.y * 128;
  const u16* Bw = (sel==0)?W0:((sel==1)?W1:W2);
  const float* bias = (sel==0)?b0:((sel==1)?b1:b2);
  const int w = tid>>6, l = tid&63;
  const int lr = l&15, lg = l>>4;
  const int wm = (w&1)*64, wn = (w>>1)*64;
  const u16* Ab = A  + (size_t)m0*1024 + (size_t)(l>>2)*1024 + (l&3)*8;
  const u16* Bb = Bw + (size_t)n0*1024 + (size_t)(l>>2)*1024 + (l&3)*8;
  f32x4 acc[4][4] = {};

#define G_STAGE(k0, pb) do {                                                    \
    _Pragma("unroll")                                                           \
    for (int i_ = 0; i_ < 2; ++i_){                                             \
      int c_ = w*2 + i_;                                                        \
      G_STAGE_ONE(Ab, As, c_, k0, pb); G_STAGE_ONE(Bb, Bs, c_, k0, pb);         \
    } } while(0)
#ifdef HAS_GLLDS
#define G_STAGE_ONE(SRC, DST, c_, k0, pb) \
    gl_lds16(SRC + (size_t)(16*(c_))*1024 + (k0), &DST[pb][(c_)*512])
#else
#define G_STAGE_ONE(SRC, DST, c_, k0, pb) \
    *(uint4*)&DST[pb][(c_)*512 + l*8] = *(const uint4*)(SRC + (size_t)(16*(c_))*1024 + (k0))
#endif

  G_STAGE(0, 0);
  __syncthreads();
  for (int it = 0; it < 32; ++it){
    const int pb = it & 1;
    if (it < 31) G_STAGE((it+1)*32, pb^1);
    short8 af[4], bf[4];
#pragma unroll
    for (int mi=0;mi<4;++mi) af[mi] = *(const short8*)&As[pb][(wm+16*mi+lr)*32 + 8*lg];
#pragma unroll
    for (int ni=0;ni<4;++ni) bf[ni] = *(const short8*)&Bs[pb][(wn+16*ni+lr)*32 + 8*lg];
#pragma unroll
    for (int mi=0;mi<4;++mi)
#pragma unroll
      for (int ni=0;ni<4;++ni)
        acc[mi][ni] = __builtin_amdgcn_mfma_f32_16x16x32_bf16(af[mi], bf[ni], acc[mi][ni], 0,0,0);
    __syncthreads();
  }

  float bv[4];
#pragma unroll
  for (int ni=0;ni<4;++ni) bv[ni] = bias[n0+wn+16*ni+lr];
  void* C = QKV ? ((sel==0)?o0:((sel==1)?o1:o2)) : o0;
#pragma unroll
  for (int mi=0;mi<4;++mi)
#pragma unroll
    for (int r=0;r<4;++r){
      const int trow = m0 + wm + 16*mi + 4*lg + r;
#pragma unroll
      for (int ni=0;ni<4;++ni){
        float v = acc[mi][ni][r] + bv[ni];
        int n = n0 + wn + 16*ni + lr;
        if (!QKV){
          ((float*)C)[(size_t)trow*1024 + n] = v;
        } else if (sel == 0){          // Q: pre-scale for exp2 softmax
          ((u16*)C)[(size_t)trow*1024 + n] = f2bf(v * QSCALE);
        } else {                       // K, V: natural
          ((u16*)C)[(size_t)trow*1024 + n] = f2bf(v);
        }
      }
    }
#undef G_STAGE
#undef G_STAGE_ONE
}

// ---------------- V transpose: V[B,T,H,DK] -> VT[B,H,DK,T], per-64-chunk k-perm ----
// position p within each 64-chunk holds source row perm^{-1}(p): p = 4*(k&15)+(k>>4)
__global__ __launch_bounds__(256) void transpose_v_k(const u16* __restrict__ V,
                                                     u16* __restrict__ VT){
  __shared__ u16 L[64 * 72];
  const int tid = threadIdx.x;
  const int tc = blockIdx.x, h = blockIdx.y, b = blockIdx.z;
#pragma unroll
  for (int p = 0; p < 2; ++p){
    int row = (tid >> 3) + 32 * p, g = tid & 7;
    *(uint4*)&L[row * 72 + g * 8] =
        *(const uint4*)(V + ((size_t)(b * T_ + tc * 64 + row) * H_ + h) * DK_ + g * 8);
  }
  __syncthreads();
#pragma unroll
  for (int p = 0; p < 2; ++p){
    int d = tid >> 2, g8 = (tid & 3) + 4 * p;
    union { uint4 u; u16 s[8]; } tv;
#pragma unroll
    for (int i = 0; i < 8; ++i){
      int pp = 8 * g8 + i;
      int tl = 16 * (pp & 3) + (pp >> 2);   // inverse perm
      tv.s[i] = L[tl * 72 + d];
    }
    *(uint4*)(VT + ((size_t)(b * H_ + h) * DK_ + d) * T_ + tc * 64 + 8 * g8) = tv.u;
  }
}

// ---------------- causal flash attention, stage-less / barrier-free ----------------
// Wave = 16 q-rows; block = 4 waves = 64 rows. K/V fragments read directly from
// global (L1/L2-resident; 64B-contiguous per row). Only LDS use: wave-private P
// round-trip (lgkm-ordered, no __syncthreads in the loop). No max-tracking; exp2.
#define PP 68
__global__ __launch_bounds__(256, 4) void attn_v4(
    const u16* __restrict__ Q, const u16* __restrict__ K,
    const u16* __restrict__ VT, u16* __restrict__ O)
{
  __shared__ u16 Ps[4][16 * PP];
  const int tid = threadIdx.x;
  const int w = tid >> 6, l = tid & 63;
  const int lr = l & 15, lg = l >> 4;
  const int h = blockIdx.y, b = blockIdx.z;
  const int qtb = 31 - blockIdx.x;           // LPT: longest q-tiles dispatch first
  const int wr0 = qtb * 64 + 16 * w;
  const size_t kbase = ((size_t)(b * T_) * H_ + h) * DK_;
  const size_t vbase = (size_t)(b * H_ + h) * DK_ * (size_t)T_;

  // Q fragments (pre-scaled): rows wr0+lr, d-chunks 32s+8lg
  short8 qf[2];
#pragma unroll
  for (int s = 0; s < 2; ++s)
    qf[s] = *(const short8*)(Q + kbase + (size_t)(wr0 + lr) * 1024 + s * 32 + 8 * lg);

  f32x4 acc[4] = {};
  float lsum[4] = {};

  for (int kt = 0; kt <= qtb; ++kt){
    // QK^T: K fragments straight from global
    short8 kf[4][2];
#pragma unroll
    for (int j0 = 0; j0 < 4; ++j0)
#pragma unroll
      for (int s = 0; s < 2; ++s)
        kf[j0][s] = *(const short8*)(K + kbase + (size_t)(kt * 64 + j0 * 16 + lr) * 1024 + s * 32 + 8 * lg);
    f32x4 sc[4];
#pragma unroll
    for (int j0 = 0; j0 < 4; ++j0){
      f32x4 z = {};
      z = __builtin_amdgcn_mfma_f32_16x16x32_bf16(qf[0], kf[j0][0], z, 0, 0, 0);
      z = __builtin_amdgcn_mfma_f32_16x16x32_bf16(qf[1], kf[j0][1], z, 0, 0, 0);
      sc[j0] = z;
    }
    // softmax numerators (exp2 only; mask on the single diagonal tile)
    const bool diag = (kt == qtb);
#pragma unroll
    for (int r = 0; r < 4; ++r){
      float p0, p1, p2, p3;
      if (diag){
        const int lim = 16 * w + 4 * lg + r;   // col idx 16*j0+lr valid iff <= lim
        p0 = (lr      <= lim) ? EXP2(sc[0][r]) : 0.f;
        p1 = (16 + lr <= lim) ? EXP2(sc[1][r]) : 0.f;
        p2 = (32 + lr <= lim) ? EXP2(sc[2][r]) : 0.f;
        p3 = (48 + lr <= lim) ? EXP2(sc[3][r]) : 0.f;
      } else {
        p0 = EXP2(sc[0][r]); p1 = EXP2(sc[1][r]);
        p2 = EXP2(sc[2][r]); p3 = EXP2(sc[3][r]);
      }
      lsum[r] += (p0 + p1) + (p2 + p3);
      u64 pv = (u64)cvtpk(p0, p1) | ((u64)cvtpk(p2, p3) << 32);  // perm cols 4lr..4lr+3
      *(u64*)&Ps[w][(4 * lg + r) * PP + 4 * lr] = pv;
    }
    // PV: A = P (perm k-slots, wave-private LDS), B = V^T global (matching perm)
#pragma unroll
    for (int ks = 0; ks < 2; ++ks){
      short8 pf = *(const short8*)&Ps[w][lr * PP + 32 * ks + 8 * lg];
#pragma unroll
      for (int d0 = 0; d0 < 4; ++d0){
        short8 vf = *(const short8*)(VT + vbase + (size_t)(d0 * 16 + lr) * T_ + kt * 64 + 32 * ks + 8 * lg);
        acc[d0] = __builtin_amdgcn_mfma_f32_16x16x32_bf16(pf, vf, acc[d0], 0, 0, 0);
      }
    }
  }

  // epilogue: one cross-lane reduce, normalize, store
#pragma unroll
  for (int r = 0; r < 4; ++r){
    float v = lsum[r];
    v += __shfl_xor(v, 1); v += __shfl_xor(v, 2);
    v += __shfl_xor(v, 4); v += __shfl_xor(v, 8);
    lsum[r] = 1.0f / v;
  }
#pragma unroll
  for (int d0 = 0; d0 < 4; ++d0)
#pragma unroll
    for (int r = 0; r < 4; ++r){
      float ov = acc[d0][r] * lsum[r];
      O[kbase + (size_t)(wr0 + 4 * lg + r) * 1024 + d0 * 16 + lr] = f2bf(ov);
    }
}

// ---------------- launcher ----------------
extern "C" void kernel_launch(void* const* d_in, const int* in_sizes, int n_in,
                              void* d_out, int out_size, void* d_ws, size_t ws_size,
                              hipStream_t stream)
{
  const float* x  = (const float*)d_in[0];
  const float* Wq = (const float*)d_in[2];
  const float* bq = (const float*)d_in[3];
  const float* Wk = (const float*)d_in[4];
  const float* bk = (const float*)d_in[5];
  const float* Wv = (const float*)d_in[6];
  const float* bv = (const float*)d_in[7];
  const float* Wo = (const float*)d_in[8];
  const float* bo = (const float*)d_in[9];

  char* ws = (char*)d_ws;
  u16* xb  = (u16*)(ws + 0);         // [0,8M)   x bf16; dead after QKV GEMM
  u16* wqb = (u16*)(ws + 8388608);
  u16* wkb = (u16*)(ws + 10485760);
  u16* wvb = (u16*)(ws + 12582912);
  u16* wob = (u16*)(ws + 14680064);
  u16* qb  = (u16*)(ws + 16777216);  // Q pre-scaled
  u16* kb  = (u16*)(ws + 25165824);  // K natural
  u16* vb  = (u16*)(ws + 33554432);  // V natural; dead after transpose
  u16* vtb = xb;                     // alias: V^T (k-perm) after QKV GEMM
  u16* ab  = vb;                     // alias: attention output

  conv_all<<<8192, 256, 0, stream>>>(x, Wq, Wk, Wv, Wo, xb, wqb, wkb, wvb, wob);

  gemm_k3<1><<<dim3(24, 32), 256, 0, stream>>>(
      xb, wqb, wkb, wvb, bq, bk, bv, (void*)qb, (void*)kb, (void*)vb);

  transpose_v_k<<<dim3(T_/64, H_, B_), 256, 0, stream>>>(vb, vtb);

  attn_v4<<<dim3(T_/64, H_, B_), 256, 0, stream>>>(qb, kb, vtb, ab);

  gemm_k3<0><<<dim3(8, 32), 256, 0, stream>>>(
      ab, wob, wob, wob, bo, bo, bo, d_out, d_out, d_out);
}

// Round 5
// 137.259 us; speedup vs baseline: 2.2080x; 2.2080x over previous
//
#include <hip/hip_runtime.h>

typedef unsigned short u16;
typedef unsigned int u32;
typedef unsigned long long u64;
typedef __attribute__((ext_vector_type(8))) short short8;
typedef __attribute__((ext_vector_type(4))) float f32x4;

#define B_ 2
#define T_ 2048
#define H_ 16
#define DK_ 64
#define QSCALE 0.18033688011112042f  // 0.125 * log2(e)

__device__ __forceinline__ u16 f2bf(float f){
  unsigned u = __float_as_uint(f);
  return (u16)((u + 0x7fffu + ((u >> 16) & 1u)) >> 16);
}

__device__ __forceinline__ u32 cvtpk(float lo, float hi){
  u32 r;
  asm("v_cvt_pk_bf16_f32 %0, %1, %2" : "=v"(r) : "v"(lo), "v"(hi));
  return r;
}

#define EXP2(x) __builtin_exp2f(x)

#if defined(__has_builtin)
#if __has_builtin(__builtin_amdgcn_global_load_lds)
#define HAS_GLLDS 1
#endif
#endif

#ifdef HAS_GLLDS
__device__ __forceinline__ void gl_lds16(const u16* g, u16* l){
  __builtin_amdgcn_global_load_lds(
      (__attribute__((address_space(1))) void*)(void*)g,
      (__attribute__((address_space(3))) void*)(void*)l, 16, 0, 0);
}
// counted-vmcnt pipeline primitives (T4): never drain to 0 mid-loop
__device__ __forceinline__ void wait_vm4(){ asm volatile("s_waitcnt vmcnt(4)" ::: "memory"); }
__device__ __forceinline__ void wait_vm0(){ asm volatile("s_waitcnt vmcnt(0)" ::: "memory"); }
__device__ __forceinline__ void pipe_bar(){
  asm volatile("" ::: "memory");
  __builtin_amdgcn_s_barrier();
  asm volatile("" ::: "memory");
}
#else
__device__ __forceinline__ void wait_vm4(){}
__device__ __forceinline__ void wait_vm0(){}
__device__ __forceinline__ void pipe_bar(){ __syncthreads(); }
#endif

// ---------------- fused fp32 -> bf16 convert (x + 4 weights) ----------------
__global__ __launch_bounds__(256) void conv_all(
    const float* __restrict__ x, const float* __restrict__ wq, const float* __restrict__ wk,
    const float* __restrict__ wv, const float* __restrict__ wo,
    u16* __restrict__ xb, u16* __restrict__ wqb, u16* __restrict__ wkb,
    u16* __restrict__ wvb, u16* __restrict__ wob)
{
  int gid = blockIdx.x * 256 + threadIdx.x;
  const float* src; u16* dst; int off;
  if (gid < 1048576){ src = x; dst = xb; off = gid; }
  else {
    int t = gid - 1048576; int s = t >> 18; off = t & 262143;
    src = (s==0)?wq:((s==1)?wk:((s==2)?wv:wo));
    dst = (s==0)?wqb:((s==1)?wkb:((s==2)?wvb:wob));
  }
  float4 v = ((const float4*)src)[off];
  u64 r = (u64)f2bf(v.x) | ((u64)f2bf(v.y)<<16) | ((u64)f2bf(v.z)<<32) | ((u64)f2bf(v.w)<<48);
  ((u64*)dst)[off] = r;
}

// ---------------- GEMM: C[M,1024] = A[M,1024]*W^T + bias ----------------
// 128x128 tile, BK=32, 3-buffer LDS, counted-vmcnt pipeline (prefetch dist 2).
// QKV=1: fused Q/K/V (grid.x=24); Q pre-scaled, K col-swizzled. QKV=0: fp32 out.
template<int QKV>
__global__ __launch_bounds__(256, 3) void gemm_k5(
    const u16* __restrict__ A,
    const u16* __restrict__ W0, const u16* __restrict__ W1, const u16* __restrict__ W2,
    const float* __restrict__ b0, const float* __restrict__ b1, const float* __restrict__ b2,
    void* __restrict__ o0, void* __restrict__ o1, void* __restrict__ o2)
{
  __shared__ u16 As[3 * 4096];
  __shared__ u16 Bs[3 * 4096];
  const int tid = threadIdx.x;
  const int sel = QKV ? (blockIdx.x >> 3) : 0;
  const int n0 = (blockIdx.x & 7) * 128;
  const int m0 = blockIdx.y * 128;
  const u16* Bw = (sel==0)?W0:((sel==1)?W1:W2);
  const float* bias = (sel==0)?b0:((sel==1)?b1:b2);
  const int w = tid>>6, l = tid&63;
  const int lr = l&15, lg = l>>4;
  const int wm = (w&1)*64, wn = (w>>1)*64;
  const u16* Ab = A  + (size_t)m0*1024 + (size_t)(l>>2)*1024 + (l&3)*8;
  const u16* Bb = Bw + (size_t)n0*1024 + (size_t)(l>>2)*1024 + (l&3)*8;
  f32x4 acc[4][4] = {};

  auto STAGE = [&](int t, int pb){
#pragma unroll
    for (int i = 0; i < 2; ++i){
      int c = w*2 + i;
#ifdef HAS_GLLDS
      gl_lds16(Ab + (size_t)(16*c)*1024 + t*32, &As[pb*4096 + c*512]);
      gl_lds16(Bb + (size_t)(16*c)*1024 + t*32, &Bs[pb*4096 + c*512]);
#else
      *(uint4*)&As[pb*4096 + c*512 + l*8] = *(const uint4*)(Ab + (size_t)(16*c)*1024 + t*32);
      *(uint4*)&Bs[pb*4096 + c*512 + l*8] = *(const uint4*)(Bb + (size_t)(16*c)*1024 + t*32);
#endif
    }
  };

  STAGE(0, 0); STAGE(1, 1);
  wait_vm4();            // tile 0 landed (4 newest = tile 1 may fly)
  pipe_bar();
  for (int it = 0; it < 32; ++it){
    const int pb = it % 3;
    if (it < 30) STAGE(it + 2, (it + 2) % 3);
    short8 af[4], bf[4];
#pragma unroll
    for (int mi=0;mi<4;++mi) af[mi] = *(const short8*)&As[pb*4096 + (wm+16*mi+lr)*32 + 8*lg];
#pragma unroll
    for (int ni=0;ni<4;++ni) bf[ni] = *(const short8*)&Bs[pb*4096 + (wn+16*ni+lr)*32 + 8*lg];
#pragma unroll
    for (int mi=0;mi<4;++mi)
#pragma unroll
      for (int ni=0;ni<4;++ni)
        acc[mi][ni] = __builtin_amdgcn_mfma_f32_16x16x32_bf16(af[mi], bf[ni], acc[mi][ni], 0,0,0);
    if (it < 31){
      if (it < 30) wait_vm4();   // tile it+1 landed, tile it+2 still in flight
      else         wait_vm0();   // epilogue drain
      pipe_bar();
    }
  }

  float bv[4];
#pragma unroll
  for (int ni=0;ni<4;++ni) bv[ni] = bias[n0+wn+16*ni+lr];
  void* C = QKV ? ((sel==0)?o0:((sel==1)?o1:o2)) : o0;
#pragma unroll
  for (int mi=0;mi<4;++mi)
#pragma unroll
    for (int r=0;r<4;++r){
      const int trow = m0 + wm + 16*mi + 4*lg + r;
#pragma unroll
      for (int ni=0;ni<4;++ni){
        float v = acc[mi][ni][r] + bv[ni];
        int n = n0 + wn + 16*ni + lr;
        if (!QKV){
          ((float*)C)[(size_t)trow*1024 + n] = v;
        } else if (sel == 0){          // Q: pre-scale for exp2 softmax
          ((u16*)C)[(size_t)trow*1024 + n] = f2bf(v * QSCALE);
        } else if (sel == 1){          // K: bank-swizzle dk within each head
          int nsw = (n & ~63) | ((n & 63) ^ ((trow & 7) << 3));
          ((u16*)C)[(size_t)trow*1024 + nsw] = f2bf(v);
        } else {                       // V: natural
          ((u16*)C)[(size_t)trow*1024 + n] = f2bf(v);
        }
      }
    }
}

// ---------------- V transpose: V[B,T,H,DK] -> VT[B,H,DK,T], per-64-chunk perm + XOR swizzle ----
__global__ __launch_bounds__(256) void transpose_v_k(const u16* __restrict__ V,
                                                     u16* __restrict__ VT){
  __shared__ u16 L[64 * 72];
  const int tid = threadIdx.x;
  const int tc = blockIdx.x, h = blockIdx.y, b = blockIdx.z;
#pragma unroll
  for (int p = 0; p < 2; ++p){
    int row = (tid >> 3) + 32 * p, g = tid & 7;
    *(uint4*)&L[row * 72 + g * 8] =
        *(const uint4*)(V + ((size_t)(b * T_ + tc * 64 + row) * H_ + h) * DK_ + g * 8);
  }
  __syncthreads();
#pragma unroll
  for (int p = 0; p < 2; ++p){
    int d = tid >> 2, g8 = (tid & 3) + 4 * p;
    union { uint4 u; u16 s[8]; } tv;
#pragma unroll
    for (int i = 0; i < 8; ++i){
      int pp = 8 * g8 + i;
      int tl = 16 * (pp & 3) + (pp >> 2);   // inverse perm
      tv.s[i] = L[tl * 72 + d];
    }
    *(uint4*)(VT + ((size_t)(b * H_ + h) * DK_ + d) * T_ + tc * 64 + ((8 * g8) ^ ((d & 7) << 3))) = tv.u;
  }
}

// ---------------- causal flash attention, 3-buffer counted-vmcnt staging ----------------
// QBLK=128 (4 waves x 32 rows), KVBLK=64. No max-tracking; exp2 (Q pre-scaled).
// K/VT globals pre-swizzled -> linear gl_lds staging + XOR'ed conflict-free reads.
__global__ __launch_bounds__(256, 2) void attn_v5(
    const u16* __restrict__ Q, const u16* __restrict__ K,
    const u16* __restrict__ VT, u16* __restrict__ O)
{
  __shared__ u16 Ks[3 * 4096];
  __shared__ u16 VTs[3 * 4096];
  __shared__ u16 Ps[4][32 * 72];
  const int tid = threadIdx.x;
  const int w = tid>>6, l = tid&63;
  const int lr = l&15, lg = l>>4;
  const int h = blockIdx.y, b = blockIdx.z;
  const int qtb = (b==0) ? blockIdx.x : (15 - blockIdx.x);  // pair long+short per CU
  const int q0 = qtb * 128;
  const int wrow0 = q0 + w*32;
  const int sl_r = l>>3, sl_c = (l&7)*8;
  const size_t kbase = ((size_t)(b*T_) * H_ + h) * DK_;
  const size_t vbase = (size_t)(b*H_ + h) * DK_ * (size_t)T_;

  auto STAGE = [&](int kt, int pb){
#pragma unroll
    for (int p=0;p<2;++p){
      int r0 = 8*w + 32*p;
#ifdef HAS_GLLDS
      gl_lds16(K  + kbase + (size_t)(kt*64 + r0 + sl_r)*1024 + sl_c, &Ks[pb*4096 + r0*64]);
      gl_lds16(VT + vbase + (size_t)(r0 + sl_r)*T_ + kt*64 + sl_c, &VTs[pb*4096 + r0*64]);
#else
      *(uint4*)&Ks[pb*4096 + (r0+sl_r)*64 + sl_c] =
          *(const uint4*)(K + kbase + (size_t)(kt*64 + r0 + sl_r)*1024 + sl_c);
      *(uint4*)&VTs[pb*4096 + (r0+sl_r)*64 + sl_c] =
          *(const uint4*)(VT + vbase + (size_t)(r0 + sl_r)*T_ + kt*64 + sl_c);
#endif
    }
  };

  // Q fragments (pre-scaled): rows wrow0 + 16mi + lr, d-slices s
  short8 qf[2][2];
#pragma unroll
  for (int mi=0;mi<2;++mi)
#pragma unroll
    for (int s=0;s<2;++s)
      qf[mi][s] = *(const short8*)(Q + kbase + (size_t)(wrow0 + 16*mi + lr)*1024 + s*32 + 8*lg);

  f32x4 acc[2][4] = {};
  float lsum[2][4] = {};
  const int ktend = 2*qtb + 1;

  STAGE(0, 0); STAGE(1, 1);
  wait_vm4();
  pipe_bar();
  for (int kt = 0; kt <= ktend; ++kt){
    const int pb = kt % 3;
    const bool more2 = (kt + 2 <= ktend);
    if (more2) STAGE(kt + 2, (kt + 2) % 3);
    if (kt*64 <= wrow0 + 31){
      // QK^T (swizzled K reads)
      short8 kf[4][2];
#pragma unroll
      for (int j0=0;j0<4;++j0)
#pragma unroll
        for (int s=0;s<2;++s)
          kf[j0][s] = *(const short8*)&Ks[pb*4096 + (j0*16+lr)*64 + (((4*s+lg) ^ (lr&7))<<3)];
      f32x4 sc[2][4];
#pragma unroll
      for (int mi=0;mi<2;++mi)
#pragma unroll
        for (int j0=0;j0<4;++j0){
          f32x4 z = {};
          z = __builtin_amdgcn_mfma_f32_16x16x32_bf16(qf[mi][0], kf[j0][0], z, 0,0,0);
          z = __builtin_amdgcn_mfma_f32_16x16x32_bf16(qf[mi][1], kf[j0][1], z, 0,0,0);
          sc[mi][j0] = z;
        }
      const bool diag = (kt*64 + 63 > wrow0);
#pragma unroll
      for (int mi=0;mi<2;++mi)
#pragma unroll
        for (int r=0;r<4;++r){
          float p0,p1,p2,p3;
          if (diag){
            const int lim = wrow0 + 16*mi + 4*lg + r - kt*64;
            p0 = (lr      <= lim) ? EXP2(sc[mi][0][r]) : 0.f;
            p1 = (16+lr   <= lim) ? EXP2(sc[mi][1][r]) : 0.f;
            p2 = (32+lr   <= lim) ? EXP2(sc[mi][2][r]) : 0.f;
            p3 = (48+lr   <= lim) ? EXP2(sc[mi][3][r]) : 0.f;
          } else {
            p0 = EXP2(sc[mi][0][r]); p1 = EXP2(sc[mi][1][r]);
            p2 = EXP2(sc[mi][2][r]); p3 = EXP2(sc[mi][3][r]);
          }
          lsum[mi][r] += (p0+p1)+(p2+p3);
          u64 pv = (u64)cvtpk(p0,p1) | ((u64)cvtpk(p2,p3) << 32);  // perm cols 4lr..4lr+3
          *(u64*)&Ps[w][(16*mi+4*lg+r)*72 + 4*lr] = pv;
        }
      // PV: A=P (perm k-slots), B=V^T (same perm slots, XOR-swizzled phys)
#pragma unroll
      for (int ks=0;ks<2;++ks){
        short8 pf0 = *(const short8*)&Ps[w][lr*72      + 32*ks + 8*lg];
        short8 pf1 = *(const short8*)&Ps[w][(16+lr)*72 + 32*ks + 8*lg];
#pragma unroll
        for (int d0=0;d0<4;++d0){
          short8 vf = *(const short8*)&VTs[pb*4096 + (d0*16+lr)*64 + (((4*ks+lg) ^ (lr&7))<<3)];
          acc[0][d0] = __builtin_amdgcn_mfma_f32_16x16x32_bf16(pf0, vf, acc[0][d0], 0,0,0);
          acc[1][d0] = __builtin_amdgcn_mfma_f32_16x16x32_bf16(pf1, vf, acc[1][d0], 0,0,0);
        }
      }
    }
    if (kt < ktend){
      if (more2) wait_vm4();   // tile kt+1 landed; kt+2 still in flight
      else       wait_vm0();   // drain tail
      pipe_bar();
    }
  }

  // epilogue: one cross-lane reduce, normalize, store
#pragma unroll
  for (int mi=0;mi<2;++mi)
#pragma unroll
    for (int r=0;r<4;++r){
      float v = lsum[mi][r];
      v += __shfl_xor(v,1); v += __shfl_xor(v,2);
      v += __shfl_xor(v,4); v += __shfl_xor(v,8);
      lsum[mi][r] = 1.0f / v;
    }
#pragma unroll
  for (int mi=0;mi<2;++mi)
#pragma unroll
    for (int d0=0;d0<4;++d0)
#pragma unroll
      for (int r=0;r<4;++r){
        float ov = acc[mi][d0][r] * lsum[mi][r];
        O[kbase + (size_t)(wrow0 + 16*mi + 4*lg + r)*1024 + d0*16 + lr] = f2bf(ov);
      }
}

// ---------------- launcher ----------------
extern "C" void kernel_launch(void* const* d_in, const int* in_sizes, int n_in,
                              void* d_out, int out_size, void* d_ws, size_t ws_size,
                              hipStream_t stream)
{
  const float* x  = (const float*)d_in[0];
  const float* Wq = (const float*)d_in[2];
  const float* bq = (const float*)d_in[3];
  const float* Wk = (const float*)d_in[4];
  const float* bk = (const float*)d_in[5];
  const float* Wv = (const float*)d_in[6];
  const float* bv = (const float*)d_in[7];
  const float* Wo = (const float*)d_in[8];
  const float* bo = (const float*)d_in[9];

  char* ws = (char*)d_ws;
  u16* xb  = (u16*)(ws + 0);         // [0,8M)   x bf16; dead after QKV GEMM
  u16* wqb = (u16*)(ws + 8388608);
  u16* wkb = (u16*)(ws + 10485760);
  u16* wvb = (u16*)(ws + 12582912);
  u16* wob = (u16*)(ws + 14680064);
  u16* qb  = (u16*)(ws + 16777216);  // Q pre-scaled
  u16* kb  = (u16*)(ws + 25165824);  // K swizzled
  u16* vb  = (u16*)(ws + 33554432);  // V natural; dead after transpose
  u16* vtb = xb;                     // alias: V^T (perm+XOR) after QKV GEMM
  u16* ab  = vb;                     // alias: attention output

  conv_all<<<8192, 256, 0, stream>>>(x, Wq, Wk, Wv, Wo, xb, wqb, wkb, wvb, wob);

  gemm_k5<1><<<dim3(24, 32), 256, 0, stream>>>(
      xb, wqb, wkb, wvb, bq, bk, bv, (void*)qb, (void*)kb, (void*)vb);

  transpose_v_k<<<dim3(T_/64, H_, B_), 256, 0, stream>>>(vb, vtb);

  attn_v5<<<dim3(T_/128, H_, B_), 256, 0, stream>>>(qb, kb, vtb, ab);

  gemm_k5<0><<<dim3(8, 32), 256, 0, stream>>>(
      ab, wob, wob, wob, bo, bo, bo, d_out, d_out, d_out);
}

// Round 6
// 133.816 us; speedup vs baseline: 2.2648x; 1.0257x over previous
//
#include <hip/hip_runtime.h>

typedef unsigned short u16;
typedef unsigned int u32;
typedef unsigned long long u64;
typedef __attribute__((ext_vector_type(8))) short short8;
typedef __attribute__((ext_vector_type(4))) float f32x4;

#define B_ 2
#define T_ 2048
#define H_ 16
#define DK_ 64
#define QSCALE 0.18033688011112042f  // 0.125 * log2(e)

__device__ __forceinline__ u16 f2bf(float f){
  unsigned u = __float_as_uint(f);
  return (u16)((u + 0x7fffu + ((u >> 16) & 1u)) >> 16);
}

__device__ __forceinline__ u32 cvtpk(float lo, float hi){
  u32 r;
  asm("v_cvt_pk_bf16_f32 %0, %1, %2" : "=v"(r) : "v"(lo), "v"(hi));
  return r;
}

// pack two f32x4 p-vectors into one bf16 A-fragment (8 elems)
__device__ __forceinline__ short8 pack8(const f32x4 a, const f32x4 b){
  union { u32 u[4]; short8 s; } t;
  t.u[0] = cvtpk(a[0], a[1]); t.u[1] = cvtpk(a[2], a[3]);
  t.u[2] = cvtpk(b[0], b[1]); t.u[3] = cvtpk(b[2], b[3]);
  return t.s;
}

#define EXP2(x) __builtin_exp2f(x)

#if defined(__has_builtin)
#if __has_builtin(__builtin_amdgcn_global_load_lds)
#define HAS_GLLDS 1
#endif
#endif

#ifdef HAS_GLLDS
__device__ __forceinline__ void gl_lds16(const u16* g, u16* l){
  __builtin_amdgcn_global_load_lds(
      (__attribute__((address_space(1))) void*)(void*)g,
      (__attribute__((address_space(3))) void*)(void*)l, 16, 0, 0);
}
__device__ __forceinline__ void wait_vm4(){ asm volatile("s_waitcnt vmcnt(4)" ::: "memory"); }
__device__ __forceinline__ void wait_vm0(){ asm volatile("s_waitcnt vmcnt(0)" ::: "memory"); }
__device__ __forceinline__ void pipe_bar(){
  asm volatile("" ::: "memory");
  __builtin_amdgcn_s_barrier();
  asm volatile("" ::: "memory");
}
#else
__device__ __forceinline__ void wait_vm4(){}
__device__ __forceinline__ void wait_vm0(){}
__device__ __forceinline__ void pipe_bar(){ __syncthreads(); }
#endif

// ---------------- fused fp32 -> bf16 convert (x + 4 weights) ----------------
__global__ __launch_bounds__(256) void conv_all(
    const float* __restrict__ x, const float* __restrict__ wq, const float* __restrict__ wk,
    const float* __restrict__ wv, const float* __restrict__ wo,
    u16* __restrict__ xb, u16* __restrict__ wqb, u16* __restrict__ wkb,
    u16* __restrict__ wvb, u16* __restrict__ wob)
{
  int gid = blockIdx.x * 256 + threadIdx.x;
  const float* src; u16* dst; int off;
  if (gid < 1048576){ src = x; dst = xb; off = gid; }
  else {
    int t = gid - 1048576; int s = t >> 18; off = t & 262143;
    src = (s==0)?wq:((s==1)?wk:((s==2)?wv:wo));
    dst = (s==0)?wqb:((s==1)?wkb:((s==2)?wvb:wob));
  }
  float4 v = ((const float4*)src)[off];
  u64 r = (u64)f2bf(v.x) | ((u64)f2bf(v.y)<<16) | ((u64)f2bf(v.z)<<32) | ((u64)f2bf(v.w)<<48);
  ((u64*)dst)[off] = r;
}

// ---------------- GEMM: C[M,1024] = A[M,1024]*W^T + bias ----------------
// 128x128 tile, BK=32, 3-buffer LDS, counted-vmcnt pipeline (prefetch dist 2).
// QKV=1: fused Q/K/V (grid.x=24); Q pre-scaled, K col-swizzled. QKV=0: fp32 out.
template<int QKV>
__global__ __launch_bounds__(256, 3) void gemm_k5(
    const u16* __restrict__ A,
    const u16* __restrict__ W0, const u16* __restrict__ W1, const u16* __restrict__ W2,
    const float* __restrict__ b0, const float* __restrict__ b1, const float* __restrict__ b2,
    void* __restrict__ o0, void* __restrict__ o1, void* __restrict__ o2)
{
  __shared__ u16 As[3 * 4096];
  __shared__ u16 Bs[3 * 4096];
  const int tid = threadIdx.x;
  const int sel = QKV ? (blockIdx.x >> 3) : 0;
  const int n0 = (blockIdx.x & 7) * 128;
  const int m0 = blockIdx.y * 128;
  const u16* Bw = (sel==0)?W0:((sel==1)?W1:W2);
  const float* bias = (sel==0)?b0:((sel==1)?b1:b2);
  const int w = tid>>6, l = tid&63;
  const int lr = l&15, lg = l>>4;
  const int wm = (w&1)*64, wn = (w>>1)*64;
  const u16* Ab = A  + (size_t)m0*1024 + (size_t)(l>>2)*1024 + (l&3)*8;
  const u16* Bb = Bw + (size_t)n0*1024 + (size_t)(l>>2)*1024 + (l&3)*8;
  f32x4 acc[4][4] = {};

  auto STAGE = [&](int t, int pb){
#pragma unroll
    for (int i = 0; i < 2; ++i){
      int c = w*2 + i;
#ifdef HAS_GLLDS
      gl_lds16(Ab + (size_t)(16*c)*1024 + t*32, &As[pb*4096 + c*512]);
      gl_lds16(Bb + (size_t)(16*c)*1024 + t*32, &Bs[pb*4096 + c*512]);
#else
      *(uint4*)&As[pb*4096 + c*512 + l*8] = *(const uint4*)(Ab + (size_t)(16*c)*1024 + t*32);
      *(uint4*)&Bs[pb*4096 + c*512 + l*8] = *(const uint4*)(Bb + (size_t)(16*c)*1024 + t*32);
#endif
    }
  };

  STAGE(0, 0); STAGE(1, 1);
  wait_vm4();
  pipe_bar();
  for (int it = 0; it < 32; ++it){
    const int pb = it % 3;
    if (it < 30) STAGE(it + 2, (it + 2) % 3);
    short8 af[4], bf[4];
#pragma unroll
    for (int mi=0;mi<4;++mi) af[mi] = *(const short8*)&As[pb*4096 + (wm+16*mi+lr)*32 + 8*lg];
#pragma unroll
    for (int ni=0;ni<4;++ni) bf[ni] = *(const short8*)&Bs[pb*4096 + (wn+16*ni+lr)*32 + 8*lg];
#pragma unroll
    for (int mi=0;mi<4;++mi)
#pragma unroll
      for (int ni=0;ni<4;++ni)
        acc[mi][ni] = __builtin_amdgcn_mfma_f32_16x16x32_bf16(af[mi], bf[ni], acc[mi][ni], 0,0,0);
    if (it < 31){
      if (it < 30) wait_vm4();
      else         wait_vm0();
      pipe_bar();
    }
  }

  float bv[4];
#pragma unroll
  for (int ni=0;ni<4;++ni) bv[ni] = bias[n0+wn+16*ni+lr];
  void* C = QKV ? ((sel==0)?o0:((sel==1)?o1:o2)) : o0;
#pragma unroll
  for (int mi=0;mi<4;++mi)
#pragma unroll
    for (int r=0;r<4;++r){
      const int trow = m0 + wm + 16*mi + 4*lg + r;
#pragma unroll
      for (int ni=0;ni<4;++ni){
        float v = acc[mi][ni][r] + bv[ni];
        int n = n0 + wn + 16*ni + lr;
        if (!QKV){
          ((float*)C)[(size_t)trow*1024 + n] = v;
        } else if (sel == 0){          // Q: pre-scale for exp2 softmax
          ((u16*)C)[(size_t)trow*1024 + n] = f2bf(v * QSCALE);
        } else if (sel == 1){          // K: bank-swizzle dk within each head
          int nsw = (n & ~63) | ((n & 63) ^ ((trow & 7) << 3));
          ((u16*)C)[(size_t)trow*1024 + nsw] = f2bf(v);
        } else {                       // V: natural
          ((u16*)C)[(size_t)trow*1024 + n] = f2bf(v);
        }
      }
    }
}

// ---------------- V transpose: V[B,T,H,DK] -> VT[B,H,DK,T] ----------------
// k-perm chosen so swapped-QK^T P registers ARE the PV A-fragments:
//   slot(k): k = 16*(2*hi+lo) + 4*c + r  ->  slot = 32*hi + 8*c + 4*lo + r
// inverse (position p -> source k): hi=(p>>5)&1, c=(p>>3)&3, lo=(p>>2)&1, r=p&3.
// Plus phys XOR swizzle ((d&7)<<3) on 8-elem chunks for conflict-free LDS reads.
__global__ __launch_bounds__(256) void transpose_v_k(const u16* __restrict__ V,
                                                     u16* __restrict__ VT){
  __shared__ u16 L[64 * 72];
  const int tid = threadIdx.x;
  const int tc = blockIdx.x, h = blockIdx.y, b = blockIdx.z;
#pragma unroll
  for (int p = 0; p < 2; ++p){
    int row = (tid >> 3) + 32 * p, g = tid & 7;
    *(uint4*)&L[row * 72 + g * 8] =
        *(const uint4*)(V + ((size_t)(b * T_ + tc * 64 + row) * H_ + h) * DK_ + g * 8);
  }
  __syncthreads();
#pragma unroll
  for (int p = 0; p < 2; ++p){
    int d = tid >> 2, g8 = (tid & 3) + 4 * p;
    union { uint4 u; u16 s[8]; } tv;
#pragma unroll
    for (int i = 0; i < 8; ++i){
      int pp = 8 * g8 + i;
      int tl = 16 * (2 * ((pp >> 5) & 1) + ((pp >> 2) & 1)) + 4 * ((pp >> 3) & 3) + (pp & 3);
      tv.s[i] = L[tl * 72 + d];
    }
    *(uint4*)(VT + ((size_t)(b * H_ + h) * DK_ + d) * T_ + tc * 64 + ((8 * g8) ^ ((d & 7) << 3))) = tv.u;
  }
}

// ---------------- causal flash attention: swapped QK^T, P fully in-register ----------------
// QBLK=128 (4 waves x 32 rows), KVBLK=64, 2-buffer staging + syncthreads (round-3 proven).
// mfma(K,Q) -> lane holds qrow=lr's scores at kcols 16j0+4lg+r; V k-perm makes the
// cvt_pk-packed registers the exact PV A-fragments. No P LDS, no per-tile shuffles.
__global__ __launch_bounds__(256, 3) void attn_v6(
    const u16* __restrict__ Q, const u16* __restrict__ K,
    const u16* __restrict__ VT, u16* __restrict__ O)
{
  __shared__ u16 Ks[2][64 * 64];
  __shared__ u16 VTs[2][64 * 64];
  const int tid = threadIdx.x;
  const int w = tid >> 6, l = tid & 63;
  const int lr = l & 15, lg = l >> 4;
  const int h = blockIdx.y, b = blockIdx.z;
  const int qtb = (b == 0) ? blockIdx.x : (15 - blockIdx.x);  // pair long+short per CU
  const int q0 = qtb * 128;
  const int wrow0 = q0 + w * 32;
  const int sl_r = l >> 3, sl_c = (l & 7) * 8;
  const size_t kbase = ((size_t)(b * T_) * H_ + h) * DK_;
  const size_t vbase = (size_t)(b * H_ + h) * DK_ * (size_t)T_;

  auto STAGE = [&](int kt, int pb){
#pragma unroll
    for (int p = 0; p < 2; ++p){
      int r0 = 8 * w + 32 * p;
#ifdef HAS_GLLDS
      gl_lds16(K  + kbase + (size_t)(kt * 64 + r0 + sl_r) * 1024 + sl_c, &Ks[pb][r0 * 64]);
      gl_lds16(VT + vbase + (size_t)(r0 + sl_r) * T_ + kt * 64 + sl_c, &VTs[pb][r0 * 64]);
#else
      *(uint4*)&Ks[pb][(r0 + sl_r) * 64 + sl_c] =
          *(const uint4*)(K + kbase + (size_t)(kt * 64 + r0 + sl_r) * 1024 + sl_c);
      *(uint4*)&VTs[pb][(r0 + sl_r) * 64 + sl_c] =
          *(const uint4*)(VT + vbase + (size_t)(r0 + sl_r) * T_ + kt * 64 + sl_c);
#endif
    }
  };

  // Q fragments (pre-scaled): B-operand, rows wrow0+16mi+lr, d-slices s
  short8 qf[2][2];
#pragma unroll
  for (int mi = 0; mi < 2; ++mi)
#pragma unroll
    for (int s = 0; s < 2; ++s)
      qf[mi][s] = *(const short8*)(Q + kbase + (size_t)(wrow0 + 16 * mi + lr) * 1024 + s * 32 + 8 * lg);

  f32x4 acc[2][4] = {};
  float lsum[2] = {0.f, 0.f};
  const int ktend = 2 * qtb + 1;

  STAGE(0, 0);
  __syncthreads();
  for (int kt = 0; kt <= ktend; ++kt){
    const int pb = kt & 1;
    if (kt < ktend) STAGE(kt + 1, pb ^ 1);
    if (kt * 64 <= wrow0 + 31){
      // QK^T swapped: A=K fragments (swizzled reads), B=Q
      short8 kf[4][2];
#pragma unroll
      for (int j0 = 0; j0 < 4; ++j0)
#pragma unroll
        for (int s = 0; s < 2; ++s)
          kf[j0][s] = *(const short8*)&Ks[pb][(j0 * 16 + lr) * 64 + (((4 * s + lg) ^ (lr & 7)) << 3)];
      short8 pf[2][2];
      const bool diag = (kt * 64 + 63 > wrow0);
      const int kc0 = kt * 64 + 4 * lg;   // lane's kcol base (+16*j0+r)
#pragma unroll
      for (int mi = 0; mi < 2; ++mi){
        f32x4 pr[4];
        float lacc = 0.f;
        const int qrow = wrow0 + 16 * mi + lr;
#pragma unroll
        for (int j0 = 0; j0 < 4; ++j0){
          f32x4 z = {};
          z = __builtin_amdgcn_mfma_f32_16x16x32_bf16(kf[j0][0], qf[mi][0], z, 0, 0, 0);
          z = __builtin_amdgcn_mfma_f32_16x16x32_bf16(kf[j0][1], qf[mi][1], z, 0, 0, 0);
#pragma unroll
          for (int r = 0; r < 4; ++r){
            float e = EXP2(z[r]);
            if (diag && (kc0 + 16 * j0 + r > qrow)) e = 0.f;
            pr[j0][r] = e;
            lacc += e;
          }
        }
        lsum[mi] += lacc;
        pf[mi][0] = pack8(pr[0], pr[1]);   // perm slots 8lg..8lg+7
        pf[mi][1] = pack8(pr[2], pr[3]);   // perm slots 32+8lg..
      }
      // PV: A = in-register P, B = V^T (matching perm slots, XOR-swizzled phys)
#pragma unroll
      for (int ks = 0; ks < 2; ++ks)
#pragma unroll
        for (int d0 = 0; d0 < 4; ++d0){
          short8 vf = *(const short8*)&VTs[pb][(d0 * 16 + lr) * 64 + (((4 * ks + lg) ^ (lr & 7)) << 3)];
          acc[0][d0] = __builtin_amdgcn_mfma_f32_16x16x32_bf16(pf[0][ks], vf, acc[0][d0], 0, 0, 0);
          acc[1][d0] = __builtin_amdgcn_mfma_f32_16x16x32_bf16(pf[1][ks], vf, acc[1][d0], 0, 0, 0);
        }
    }
    __syncthreads();
  }

  // epilogue: reduce lsum across lg groups, redistribute to acc-row lanes, store
#pragma unroll
  for (int mi = 0; mi < 2; ++mi){
    float v = lsum[mi];
    v += __shfl_xor(v, 16);
    v += __shfl_xor(v, 32);
    float inv = 1.0f / v;     // valid for qrow = wrow0+16mi+lr at every lane
    float invr[4];
#pragma unroll
    for (int r = 0; r < 4; ++r) invr[r] = __shfl(inv, 4 * lg + r);  // qrow = 4lg+r
#pragma unroll
    for (int d0 = 0; d0 < 4; ++d0)
#pragma unroll
      for (int r = 0; r < 4; ++r){
        float ov = acc[mi][d0][r] * invr[r];
        O[kbase + (size_t)(wrow0 + 16 * mi + 4 * lg + r) * 1024 + d0 * 16 + lr] = f2bf(ov);
      }
  }
}

// ---------------- launcher ----------------
extern "C" void kernel_launch(void* const* d_in, const int* in_sizes, int n_in,
                              void* d_out, int out_size, void* d_ws, size_t ws_size,
                              hipStream_t stream)
{
  const float* x  = (const float*)d_in[0];
  const float* Wq = (const float*)d_in[2];
  const float* bq = (const float*)d_in[3];
  const float* Wk = (const float*)d_in[4];
  const float* bk = (const float*)d_in[5];
  const float* Wv = (const float*)d_in[6];
  const float* bv = (const float*)d_in[7];
  const float* Wo = (const float*)d_in[8];
  const float* bo = (const float*)d_in[9];

  char* ws = (char*)d_ws;
  u16* xb  = (u16*)(ws + 0);         // [0,8M)   x bf16; dead after QKV GEMM
  u16* wqb = (u16*)(ws + 8388608);
  u16* wkb = (u16*)(ws + 10485760);
  u16* wvb = (u16*)(ws + 12582912);
  u16* wob = (u16*)(ws + 14680064);
  u16* qb  = (u16*)(ws + 16777216);  // Q pre-scaled
  u16* kb  = (u16*)(ws + 25165824);  // K swizzled
  u16* vb  = (u16*)(ws + 33554432);  // V natural; dead after transpose
  u16* vtb = xb;                     // alias: V^T (perm+XOR) after QKV GEMM
  u16* ab  = vb;                     // alias: attention output

  conv_all<<<8192, 256, 0, stream>>>(x, Wq, Wk, Wv, Wo, xb, wqb, wkb, wvb, wob);

  gemm_k5<1><<<dim3(24, 32), 256, 0, stream>>>(
      xb, wqb, wkb, wvb, bq, bk, bv, (void*)qb, (void*)kb, (void*)vb);

  transpose_v_k<<<dim3(T_/64, H_, B_), 256, 0, stream>>>(vb, vtb);

  attn_v6<<<dim3(T_/128, H_, B_), 256, 0, stream>>>(qb, kb, vtb, ab);

  gemm_k5<0><<<dim3(8, 32), 256, 0, stream>>>(
      ab, wob, wob, wob, bo, bo, bo, d_out, d_out, d_out);
}

// Round 8
// 116.301 us; speedup vs baseline: 2.6059x; 1.1506x over previous
//
#include <hip/hip_runtime.h>

typedef unsigned short u16;
typedef unsigned int u32;
typedef unsigned long long u64;
typedef __attribute__((ext_vector_type(8))) short short8;
typedef __attribute__((ext_vector_type(4))) float f32x4;

#define B_ 2
#define T_ 2048
#define H_ 16
#define DK_ 64
#define QSCALE 0.18033688011112042f  // 0.125 * log2(e)

__device__ __forceinline__ u16 f2bf(float f){
  unsigned u = __float_as_uint(f);
  return (u16)((u + 0x7fffu + ((u >> 16) & 1u)) >> 16);
}

__device__ __forceinline__ u32 cvtpk(float lo, float hi){
  u32 r;
  asm("v_cvt_pk_bf16_f32 %0, %1, %2" : "=v"(r) : "v"(lo), "v"(hi));
  return r;
}

// 2^x via the compiler's fast-exp path (v_mul+v_exp_f32 WITH proper TRANS-op
// hazard handling — raw inline-asm v_exp_f32 lacks the wait-state and corrupts
// dependent reads; that was round-7's failure).
#define EXP2(x) __expf(0.6931471805599453f * (x))

// pack two f32x4 p-vectors into one bf16 A-fragment (8 elems)
__device__ __forceinline__ short8 pack8(const f32x4 a, const f32x4 b){
  union { u32 u[4]; short8 s; } t;
  t.u[0] = cvtpk(a[0], a[1]); t.u[1] = cvtpk(a[2], a[3]);
  t.u[2] = cvtpk(b[0], b[1]); t.u[3] = cvtpk(b[2], b[3]);
  return t.s;
}

#if defined(__has_builtin)
#if __has_builtin(__builtin_amdgcn_global_load_lds)
#define HAS_GLLDS 1
#endif
#endif

#ifdef HAS_GLLDS
__device__ __forceinline__ void gl_lds16(const u16* g, u16* l){
  __builtin_amdgcn_global_load_lds(
      (__attribute__((address_space(1))) void*)(void*)g,
      (__attribute__((address_space(3))) void*)(void*)l, 16, 0, 0);
}
__device__ __forceinline__ void wait_vm4(){ asm volatile("s_waitcnt vmcnt(4)" ::: "memory"); }
__device__ __forceinline__ void wait_vm0(){ asm volatile("s_waitcnt vmcnt(0)" ::: "memory"); }
__device__ __forceinline__ void pipe_bar(){
  asm volatile("" ::: "memory");
  __builtin_amdgcn_s_barrier();
  asm volatile("" ::: "memory");
}
#else
__device__ __forceinline__ void wait_vm4(){}
__device__ __forceinline__ void wait_vm0(){}
__device__ __forceinline__ void pipe_bar(){ __syncthreads(); }
#endif

// ---------------- fused fp32 -> bf16 convert (x + 4 weights) ----------------
__global__ __launch_bounds__(256) void conv_all(
    const float* __restrict__ x, const float* __restrict__ wq, const float* __restrict__ wk,
    const float* __restrict__ wv, const float* __restrict__ wo,
    u16* __restrict__ xb, u16* __restrict__ wqb, u16* __restrict__ wkb,
    u16* __restrict__ wvb, u16* __restrict__ wob)
{
  int gid = blockIdx.x * 256 + threadIdx.x;
  const float* src; u16* dst; int off;
  if (gid < 1048576){ src = x; dst = xb; off = gid; }
  else {
    int t = gid - 1048576; int s = t >> 18; off = t & 262143;
    src = (s==0)?wq:((s==1)?wk:((s==2)?wv:wo));
    dst = (s==0)?wqb:((s==1)?wkb:((s==2)?wvb:wob));
  }
  float4 v = ((const float4*)src)[off];
  u64 r = (u64)f2bf(v.x) | ((u64)f2bf(v.y)<<16) | ((u64)f2bf(v.z)<<32) | ((u64)f2bf(v.w)<<48);
  ((u64*)dst)[off] = r;
}

// ---------------- GEMM: C[M,1024] = A[M,1024]*W^T + bias ----------------
// 128x128 tile, BK=32, 3-buffer LDS, counted-vmcnt pipeline (prefetch dist 2).
// QKV=1: fused Q/K/V (grid.x=24); Q pre-scaled, K col-swizzled. QKV=0: fp32 out.
template<int QKV>
__global__ __launch_bounds__(256, 3) void gemm_k5(
    const u16* __restrict__ A,
    const u16* __restrict__ W0, const u16* __restrict__ W1, const u16* __restrict__ W2,
    const float* __restrict__ b0, const float* __restrict__ b1, const float* __restrict__ b2,
    void* __restrict__ o0, void* __restrict__ o1, void* __restrict__ o2)
{
  __shared__ u16 As[3 * 4096];
  __shared__ u16 Bs[3 * 4096];
  const int tid = threadIdx.x;
  const int sel = QKV ? (blockIdx.x >> 3) : 0;
  const int n0 = (blockIdx.x & 7) * 128;
  const int m0 = blockIdx.y * 128;
  const u16* Bw = (sel==0)?W0:((sel==1)?W1:W2);
  const float* bias = (sel==0)?b0:((sel==1)?b1:b2);
  const int w = tid>>6, l = tid&63;
  const int lr = l&15, lg = l>>4;
  const int wm = (w&1)*64, wn = (w>>1)*64;
  const u16* Ab = A  + (size_t)m0*1024 + (size_t)(l>>2)*1024 + (l&3)*8;
  const u16* Bb = Bw + (size_t)n0*1024 + (size_t)(l>>2)*1024 + (l&3)*8;
  f32x4 acc[4][4] = {};

  auto STAGE = [&](int t, int pb){
#pragma unroll
    for (int i = 0; i < 2; ++i){
      int c = w*2 + i;
#ifdef HAS_GLLDS
      gl_lds16(Ab + (size_t)(16*c)*1024 + t*32, &As[pb*4096 + c*512]);
      gl_lds16(Bb + (size_t)(16*c)*1024 + t*32, &Bs[pb*4096 + c*512]);
#else
      *(uint4*)&As[pb*4096 + c*512 + l*8] = *(const uint4*)(Ab + (size_t)(16*c)*1024 + t*32);
      *(uint4*)&Bs[pb*4096 + c*512 + l*8] = *(const uint4*)(Bb + (size_t)(16*c)*1024 + t*32);
#endif
    }
  };

  STAGE(0, 0); STAGE(1, 1);
  wait_vm4();
  pipe_bar();
  for (int it = 0; it < 32; ++it){
    const int pb = it % 3;
    if (it < 30) STAGE(it + 2, (it + 2) % 3);
    short8 af[4], bf[4];
#pragma unroll
    for (int mi=0;mi<4;++mi) af[mi] = *(const short8*)&As[pb*4096 + (wm+16*mi+lr)*32 + 8*lg];
#pragma unroll
    for (int ni=0;ni<4;++ni) bf[ni] = *(const short8*)&Bs[pb*4096 + (wn+16*ni+lr)*32 + 8*lg];
#pragma unroll
    for (int mi=0;mi<4;++mi)
#pragma unroll
      for (int ni=0;ni<4;++ni)
        acc[mi][ni] = __builtin_amdgcn_mfma_f32_16x16x32_bf16(af[mi], bf[ni], acc[mi][ni], 0,0,0);
    if (it < 31){
      if (it < 30) wait_vm4();
      else         wait_vm0();
      pipe_bar();
    }
  }

  float bv[4];
#pragma unroll
  for (int ni=0;ni<4;++ni) bv[ni] = bias[n0+wn+16*ni+lr];
  void* C = QKV ? ((sel==0)?o0:((sel==1)?o1:o2)) : o0;
#pragma unroll
  for (int mi=0;mi<4;++mi)
#pragma unroll
    for (int r=0;r<4;++r){
      const int trow = m0 + wm + 16*mi + 4*lg + r;
#pragma unroll
      for (int ni=0;ni<4;++ni){
        float v = acc[mi][ni][r] + bv[ni];
        int n = n0 + wn + 16*ni + lr;
        if (!QKV){
          ((float*)C)[(size_t)trow*1024 + n] = v;
        } else if (sel == 0){          // Q: pre-scale for exp2 softmax
          ((u16*)C)[(size_t)trow*1024 + n] = f2bf(v * QSCALE);
        } else if (sel == 1){          // K: bank-swizzle dk within each head
          int nsw = (n & ~63) | ((n & 63) ^ ((trow & 7) << 3));
          ((u16*)C)[(size_t)trow*1024 + nsw] = f2bf(v);
        } else {                       // V: natural
          ((u16*)C)[(size_t)trow*1024 + n] = f2bf(v);
        }
      }
    }
}

// ---------------- V transpose: V[B,T,H,DK] -> VT[B,H,DK,T], 128-chunk k-perm + XOR ----
// forward: k = 32ks+16lo+4c+r -> slot = 32ks+8c+4lo+r  (so swapped-QK^T P regs ARE
// the PV A-fragments). inverse: p -> k = 32(p>>5) + 16((p>>2)&1) + 4((p>>3)&3) + (p&3).
// phys: 8-elem chunk index XOR'ed with (d&7) for conflict-free LDS reads.
__global__ __launch_bounds__(256) void transpose_v128(const u16* __restrict__ V,
                                                      u16* __restrict__ VT){
  __shared__ u16 L[128 * 72];
  const int tid = threadIdx.x;
  const int tc = blockIdx.x, h = blockIdx.y, b = blockIdx.z;
#pragma unroll
  for (int p = 0; p < 4; ++p){
    int row = (tid >> 3) + 32 * p, g = tid & 7;
    *(uint4*)&L[row * 72 + g * 8] =
        *(const uint4*)(V + ((size_t)(b * T_ + tc * 128 + row) * H_ + h) * DK_ + g * 8);
  }
  __syncthreads();
#pragma unroll
  for (int p = 0; p < 4; ++p){
    int d = tid >> 2, g8 = (tid & 3) + 4 * p;   // g8 in 0..15
    union { uint4 u; u16 s[8]; } tv;
#pragma unroll
    for (int i = 0; i < 8; ++i){
      int pp = 8 * g8 + i;
      int tl = 32 * (pp >> 5) + 16 * ((pp >> 2) & 1) + 4 * ((pp >> 3) & 3) + (pp & 3);
      tv.s[i] = L[tl * 72 + d];
    }
    *(uint4*)(VT + ((size_t)(b * H_ + h) * DK_ + d) * T_ + tc * 128 + ((8 * g8) ^ ((d & 7) << 3))) = tv.u;
  }
}

// ---------------- causal flash attention: swapped QK^T, reg-P, KVBLK=128 ----------------
// QBLK=128 (4 waves x 32 rows), KVBLK=128: every wave computes every phase (no skip);
// masking confined to the single final diagonal phase. 2-buffer staging + syncthreads.
__global__ __launch_bounds__(256, 2) void attn_v7(
    const u16* __restrict__ Q, const u16* __restrict__ K,
    const u16* __restrict__ VT, u16* __restrict__ O)
{
  __shared__ u16 Ks[2][128 * 64];
  __shared__ u16 VTs[2][64 * 128];
  const int tid = threadIdx.x;
  const int w = tid >> 6, l = tid & 63;
  const int lr = l & 15, lg = l >> 4;
  const int h = blockIdx.y, b = blockIdx.z;
  const int qtb = (b == 0) ? blockIdx.x : (15 - blockIdx.x);  // pair long+short per CU
  const int q0 = qtb * 128;
  const int wrow0 = q0 + 32 * w;
  const size_t kbase = ((size_t)(b * T_) * H_ + h) * DK_;
  const size_t vbase = (size_t)(b * H_ + h) * DK_ * (size_t)T_;

  auto STAGE = [&](int kt, int pb){
#pragma unroll
    for (int p = 0; p < 4; ++p){
      int kr0 = 32 * w + 8 * p;   // 8 K-rows per call (128B rows)
#ifdef HAS_GLLDS
      gl_lds16(K + kbase + (size_t)(kt * 128 + kr0 + (l >> 3)) * 1024 + (l & 7) * 8,
               &Ks[pb][kr0 * 64]);
#else
      *(uint4*)&Ks[pb][(kr0 + (l >> 3)) * 64 + (l & 7) * 8] =
          *(const uint4*)(K + kbase + (size_t)(kt * 128 + kr0 + (l >> 3)) * 1024 + (l & 7) * 8);
#endif
    }
#pragma unroll
    for (int p = 0; p < 4; ++p){
      int dr0 = 16 * w + 4 * p;   // 4 VT d-rows per call (256B rows)
#ifdef HAS_GLLDS
      gl_lds16(VT + vbase + (size_t)(dr0 + (l >> 4)) * T_ + kt * 128 + (l & 15) * 8,
               &VTs[pb][dr0 * 128]);
#else
      *(uint4*)&VTs[pb][(dr0 + (l >> 4)) * 128 + (l & 15) * 8] =
          *(const uint4*)(VT + vbase + (size_t)(dr0 + (l >> 4)) * T_ + kt * 128 + (l & 15) * 8);
#endif
    }
  };

  // Q fragments (pre-scaled): B-operand, rows wrow0+16mi+lr, d-slices s
  short8 qf[2][2];
#pragma unroll
  for (int mi = 0; mi < 2; ++mi)
#pragma unroll
    for (int s = 0; s < 2; ++s)
      qf[mi][s] = *(const short8*)(Q + kbase + (size_t)(wrow0 + 16 * mi + lr) * 1024 + s * 32 + 8 * lg);

  f32x4 acc[2][4] = {};
  float lsum[2] = {0.f, 0.f};
  const int ktend = qtb;

  STAGE(0, 0);
  __syncthreads();
  for (int kt = 0; kt <= ktend; ++kt){
    const int pb = kt & 1;
    if (kt < ktend) STAGE(kt + 1, pb ^ 1);
    const bool diag = (kt == ktend);   // only the final phase masks
    short8 pf[2][4];
#pragma unroll
    for (int jh = 0; jh < 2; ++jh){
      short8 kf[4][2];
#pragma unroll
      for (int j = 0; j < 4; ++j)
#pragma unroll
        for (int s = 0; s < 2; ++s)
          kf[j][s] = *(const short8*)&Ks[pb][((4 * jh + j) * 16 + lr) * 64 + (((4 * s + lg) ^ (lr & 7)) << 3)];
#pragma unroll
      for (int mi = 0; mi < 2; ++mi){
        f32x4 pr[4];
        float lacc = 0.f;
        const int lim = 32 * w + 16 * mi + lr;   // qrow - q0
#pragma unroll
        for (int j = 0; j < 4; ++j){
          const int j0 = 4 * jh + j;
          f32x4 z = {};
          z = __builtin_amdgcn_mfma_f32_16x16x32_bf16(kf[j][0], qf[mi][0], z, 0, 0, 0);
          z = __builtin_amdgcn_mfma_f32_16x16x32_bf16(kf[j][1], qf[mi][1], z, 0, 0, 0);
#pragma unroll
          for (int r = 0; r < 4; ++r){
            float e = EXP2(z[r]);
            if (diag && (16 * j0 + 4 * lg + r > lim)) e = 0.f;
            pr[j][r] = e;
            lacc += e;
          }
        }
        lsum[mi] += lacc;
        pf[mi][2 * jh]     = pack8(pr[0], pr[1]);
        pf[mi][2 * jh + 1] = pack8(pr[2], pr[3]);
      }
    }
    // PV: A = in-register P, B = V^T (matching perm slots, XOR-swizzled phys)
#pragma unroll
    for (int ks = 0; ks < 4; ++ks)
#pragma unroll
      for (int d0 = 0; d0 < 4; ++d0){
        short8 vf = *(const short8*)&VTs[pb][(d0 * 16 + lr) * 128 + (((4 * ks + lg) ^ (lr & 7)) << 3)];
        acc[0][d0] = __builtin_amdgcn_mfma_f32_16x16x32_bf16(pf[0][ks], vf, acc[0][d0], 0, 0, 0);
        acc[1][d0] = __builtin_amdgcn_mfma_f32_16x16x32_bf16(pf[1][ks], vf, acc[1][d0], 0, 0, 0);
      }
    __syncthreads();
  }

  // epilogue: reduce lsum across lg groups, redistribute to acc-row lanes, store
#pragma unroll
  for (int mi = 0; mi < 2; ++mi){
    float v = lsum[mi];
    v += __shfl_xor(v, 16);
    v += __shfl_xor(v, 32);
    float inv = 1.0f / v;     // valid for qrow = wrow0+16mi+lr at every lane
    float invr[4];
#pragma unroll
    for (int r = 0; r < 4; ++r) invr[r] = __shfl(inv, 4 * lg + r);  // provider lane 4lg+r
#pragma unroll
    for (int d0 = 0; d0 < 4; ++d0)
#pragma unroll
      for (int r = 0; r < 4; ++r){
        float ov = acc[mi][d0][r] * invr[r];
        O[kbase + (size_t)(wrow0 + 16 * mi + 4 * lg + r) * 1024 + d0 * 16 + lr] = f2bf(ov);
      }
  }
}

// ---------------- launcher ----------------
extern "C" void kernel_launch(void* const* d_in, const int* in_sizes, int n_in,
                              void* d_out, int out_size, void* d_ws, size_t ws_size,
                              hipStream_t stream)
{
  const float* x  = (const float*)d_in[0];
  const float* Wq = (const float*)d_in[2];
  const float* bq = (const float*)d_in[3];
  const float* Wk = (const float*)d_in[4];
  const float* bk = (const float*)d_in[5];
  const float* Wv = (const float*)d_in[6];
  const float* bv = (const float*)d_in[7];
  const float* Wo = (const float*)d_in[8];
  const float* bo = (const float*)d_in[9];

  char* ws = (char*)d_ws;
  u16* xb  = (u16*)(ws + 0);         // [0,8M)   x bf16; dead after QKV GEMM
  u16* wqb = (u16*)(ws + 8388608);
  u16* wkb = (u16*)(ws + 10485760);
  u16* wvb = (u16*)(ws + 12582912);
  u16* wob = (u16*)(ws + 14680064);
  u16* qb  = (u16*)(ws + 16777216);  // Q pre-scaled
  u16* kb  = (u16*)(ws + 25165824);  // K swizzled
  u16* vb  = (u16*)(ws + 33554432);  // V natural; dead after transpose
  u16* vtb = xb;                     // alias: V^T (128-chunk perm+XOR) after QKV GEMM
  u16* ab  = vb;                     // alias: attention output

  conv_all<<<8192, 256, 0, stream>>>(x, Wq, Wk, Wv, Wo, xb, wqb, wkb, wvb, wob);

  gemm_k5<1><<<dim3(24, 32), 256, 0, stream>>>(
      xb, wqb, wkb, wvb, bq, bk, bv, (void*)qb, (void*)kb, (void*)vb);

  transpose_v128<<<dim3(T_/128, H_, B_), 256, 0, stream>>>(vb, vtb);

  attn_v7<<<dim3(T_/128, H_, B_), 256, 0, stream>>>(qb, kb, vtb, ab);

  gemm_k5<0><<<dim3(8, 32), 256, 0, stream>>>(
      ab, wob, wob, wob, bo, bo, bo, d_out, d_out, d_out);
}

// Round 9
// 115.413 us; speedup vs baseline: 2.6259x; 1.0077x over previous
//
#include <hip/hip_runtime.h>

typedef unsigned short u16;
typedef unsigned int u32;
typedef unsigned long long u64;
typedef __attribute__((ext_vector_type(8))) short short8;
typedef __attribute__((ext_vector_type(4))) float f32x4;

#define B_ 2
#define T_ 2048
#define H_ 16
#define DK_ 64
#define QSCALE 0.18033688011112042f  // 0.125 * log2(e)

__device__ __forceinline__ u16 f2bf(float f){
  unsigned u = __float_as_uint(f);
  return (u16)((u + 0x7fffu + ((u >> 16) & 1u)) >> 16);
}

__device__ __forceinline__ u32 cvtpk(float lo, float hi){
  u32 r;
  asm("v_cvt_pk_bf16_f32 %0, %1, %2" : "=v"(r) : "v"(lo), "v"(hi));
  return r;
}

// 2^x via the compiler's fast-exp path (v_mul+v_exp_f32 WITH proper TRANS-op
// hazard handling — raw inline-asm v_exp_f32 lacks the wait-state and corrupts
// dependent reads; that was round-7's failure).
#define EXP2(x) __expf(0.6931471805599453f * (x))

// pack two f32x4 p-vectors into one bf16 A-fragment (8 elems)
__device__ __forceinline__ short8 pack8(const f32x4 a, const f32x4 b){
  union { u32 u[4]; short8 s; } t;
  t.u[0] = cvtpk(a[0], a[1]); t.u[1] = cvtpk(a[2], a[3]);
  t.u[2] = cvtpk(b[0], b[1]); t.u[3] = cvtpk(b[2], b[3]);
  return t.s;
}

#if defined(__has_builtin)
#if __has_builtin(__builtin_amdgcn_global_load_lds)
#define HAS_GLLDS 1
#endif
#endif

#ifdef HAS_GLLDS
__device__ __forceinline__ void gl_lds16(const u16* g, u16* l){
  __builtin_amdgcn_global_load_lds(
      (__attribute__((address_space(1))) void*)(void*)g,
      (__attribute__((address_space(3))) void*)(void*)l, 16, 0, 0);
}
__device__ __forceinline__ void wait_vm4(){ asm volatile("s_waitcnt vmcnt(4)" ::: "memory"); }
__device__ __forceinline__ void wait_vm0(){ asm volatile("s_waitcnt vmcnt(0)" ::: "memory"); }
__device__ __forceinline__ void pipe_bar(){
  asm volatile("" ::: "memory");
  __builtin_amdgcn_s_barrier();
  asm volatile("" ::: "memory");
}
#else
__device__ __forceinline__ void wait_vm4(){}
__device__ __forceinline__ void wait_vm0(){}
__device__ __forceinline__ void pipe_bar(){ __syncthreads(); }
#endif

// ---------------- fused fp32 -> bf16 convert (x + 4 weights) ----------------
__global__ __launch_bounds__(256) void conv_all(
    const float* __restrict__ x, const float* __restrict__ wq, const float* __restrict__ wk,
    const float* __restrict__ wv, const float* __restrict__ wo,
    u16* __restrict__ xb, u16* __restrict__ wqb, u16* __restrict__ wkb,
    u16* __restrict__ wvb, u16* __restrict__ wob)
{
  int gid = blockIdx.x * 256 + threadIdx.x;
  const float* src; u16* dst; int off;
  if (gid < 1048576){ src = x; dst = xb; off = gid; }
  else {
    int t = gid - 1048576; int s = t >> 18; off = t & 262143;
    src = (s==0)?wq:((s==1)?wk:((s==2)?wv:wo));
    dst = (s==0)?wqb:((s==1)?wkb:((s==2)?wvb:wob));
  }
  float4 v = ((const float4*)src)[off];
  u64 r = (u64)f2bf(v.x) | ((u64)f2bf(v.y)<<16) | ((u64)f2bf(v.z)<<32) | ((u64)f2bf(v.w)<<48);
  ((u64*)dst)[off] = r;
}

// ---------------- GEMM: C[M,1024] = A[M,1024]*W^T + bias ----------------
// 128x128 tile, BK=32, 3-buffer LDS, counted-vmcnt pipeline (prefetch dist 2).
// LDS chunk-swizzle: LDS[row][chunk] holds A[row][chunk ^ ((row>>1)&3)] via
// pre-swizzled per-lane global source (gl_lds dest stays linear, rule #21);
// reads use chunk lg^((lr>>1)&3) -> all 8 lanes of a b128 quarter-group hit
// distinct banks (was 4-way conflict = 3.15M SQ_LDS_BANK_CONFLICT).
// QKV=1: fused Q/K/V (grid.x=24); Q pre-scaled, K col-swizzled. QKV=0: fp32 out.
template<int QKV>
__global__ __launch_bounds__(256, 3) void gemm_k5(
    const u16* __restrict__ A,
    const u16* __restrict__ W0, const u16* __restrict__ W1, const u16* __restrict__ W2,
    const float* __restrict__ b0, const float* __restrict__ b1, const float* __restrict__ b2,
    void* __restrict__ o0, void* __restrict__ o1, void* __restrict__ o2)
{
  __shared__ u16 As[3 * 4096];
  __shared__ u16 Bs[3 * 4096];
  const int tid = threadIdx.x;
  const int sel = QKV ? (blockIdx.x >> 3) : 0;
  const int n0 = (blockIdx.x & 7) * 128;
  const int m0 = blockIdx.y * 128;
  const u16* Bw = (sel==0)?W0:((sel==1)?W1:W2);
  const float* bias = (sel==0)?b0:((sel==1)?b1:b2);
  const int w = tid>>6, l = tid&63;
  const int lr = l&15, lg = l>>4;
  const int wm = (w&1)*64, wn = (w>>1)*64;
  // staging source: row l>>2 within 16-row chunk, SWIZZLED 16B col chunk
  const int scol = ((l & 3) ^ ((l >> 3) & 3)) * 8;
  const u16* Ab = A  + (size_t)m0*1024 + (size_t)(l>>2)*1024 + scol;
  const u16* Bb = Bw + (size_t)n0*1024 + (size_t)(l>>2)*1024 + scol;
  // read-side swizzle for fragment loads
  const int rsw = (lr >> 1) & 3;
  f32x4 acc[4][4] = {};

  auto STAGE = [&](int t, int pb){
#pragma unroll
    for (int i = 0; i < 2; ++i){
      int c = w*2 + i;
#ifdef HAS_GLLDS
      gl_lds16(Ab + (size_t)(16*c)*1024 + t*32, &As[pb*4096 + c*512]);
      gl_lds16(Bb + (size_t)(16*c)*1024 + t*32, &Bs[pb*4096 + c*512]);
#else
      *(uint4*)&As[pb*4096 + c*512 + l*8] = *(const uint4*)(Ab + (size_t)(16*c)*1024 + t*32);
      *(uint4*)&Bs[pb*4096 + c*512 + l*8] = *(const uint4*)(Bb + (size_t)(16*c)*1024 + t*32);
#endif
    }
  };

  STAGE(0, 0); STAGE(1, 1);
  wait_vm4();
  pipe_bar();
  for (int it = 0; it < 32; ++it){
    const int pb = it % 3;
    if (it < 30) STAGE(it + 2, (it + 2) % 3);
    short8 af[4], bf[4];
#pragma unroll
    for (int mi=0;mi<4;++mi) af[mi] = *(const short8*)&As[pb*4096 + (wm+16*mi+lr)*32 + 8*(lg ^ rsw)];
#pragma unroll
    for (int ni=0;ni<4;++ni) bf[ni] = *(const short8*)&Bs[pb*4096 + (wn+16*ni+lr)*32 + 8*(lg ^ rsw)];
#pragma unroll
    for (int mi=0;mi<4;++mi)
#pragma unroll
      for (int ni=0;ni<4;++ni)
        acc[mi][ni] = __builtin_amdgcn_mfma_f32_16x16x32_bf16(af[mi], bf[ni], acc[mi][ni], 0,0,0);
    if (it < 31){
      if (it < 30) wait_vm4();
      else         wait_vm0();
      pipe_bar();
    }
  }

  float bv[4];
#pragma unroll
  for (int ni=0;ni<4;++ni) bv[ni] = bias[n0+wn+16*ni+lr];
  void* C = QKV ? ((sel==0)?o0:((sel==1)?o1:o2)) : o0;
#pragma unroll
  for (int mi=0;mi<4;++mi)
#pragma unroll
    for (int r=0;r<4;++r){
      const int trow = m0 + wm + 16*mi + 4*lg + r;
#pragma unroll
      for (int ni=0;ni<4;++ni){
        float v = acc[mi][ni][r] + bv[ni];
        int n = n0 + wn + 16*ni + lr;
        if (!QKV){
          ((float*)C)[(size_t)trow*1024 + n] = v;
        } else if (sel == 0){          // Q: pre-scale for exp2 softmax
          ((u16*)C)[(size_t)trow*1024 + n] = f2bf(v * QSCALE);
        } else if (sel == 1){          // K: bank-swizzle dk within each head
          int nsw = (n & ~63) | ((n & 63) ^ ((trow & 7) << 3));
          ((u16*)C)[(size_t)trow*1024 + nsw] = f2bf(v);
        } else {                       // V: natural
          ((u16*)C)[(size_t)trow*1024 + n] = f2bf(v);
        }
      }
    }
}

// ---------------- V transpose: V[B,T,H,DK] -> VT[B,H,DK,T], 128-chunk k-perm + XOR ----
// forward: k = 32ks+16lo+4c+r -> slot = 32ks+8c+4lo+r  (so swapped-QK^T P regs ARE
// the PV A-fragments). inverse: p -> k = 32(p>>5) + 16((p>>2)&1) + 4((p>>3)&3) + (p&3).
// phys: 8-elem chunk index XOR'ed with (d&7) for conflict-free LDS reads.
__global__ __launch_bounds__(256) void transpose_v128(const u16* __restrict__ V,
                                                      u16* __restrict__ VT){
  __shared__ u16 L[128 * 72];
  const int tid = threadIdx.x;
  const int tc = blockIdx.x, h = blockIdx.y, b = blockIdx.z;
#pragma unroll
  for (int p = 0; p < 4; ++p){
    int row = (tid >> 3) + 32 * p, g = tid & 7;
    *(uint4*)&L[row * 72 + g * 8] =
        *(const uint4*)(V + ((size_t)(b * T_ + tc * 128 + row) * H_ + h) * DK_ + g * 8);
  }
  __syncthreads();
#pragma unroll
  for (int p = 0; p < 4; ++p){
    int d = tid >> 2, g8 = (tid & 3) + 4 * p;   // g8 in 0..15
    union { uint4 u; u16 s[8]; } tv;
#pragma unroll
    for (int i = 0; i < 8; ++i){
      int pp = 8 * g8 + i;
      int tl = 32 * (pp >> 5) + 16 * ((pp >> 2) & 1) + 4 * ((pp >> 3) & 3) + (pp & 3);
      tv.s[i] = L[tl * 72 + d];
    }
    *(uint4*)(VT + ((size_t)(b * H_ + h) * DK_ + d) * T_ + tc * 128 + ((8 * g8) ^ ((d & 7) << 3))) = tv.u;
  }
}

// ---------------- causal flash attention: swapped QK^T, reg-P, KVBLK=128 ----------------
// QBLK=128 (4 waves x 32 rows), KVBLK=128: every wave computes every phase (no skip);
// masking confined to the single final diagonal phase. 2-buffer staging + syncthreads.
__global__ __launch_bounds__(256, 2) void attn_v7(
    const u16* __restrict__ Q, const u16* __restrict__ K,
    const u16* __restrict__ VT, u16* __restrict__ O)
{
  __shared__ u16 Ks[2][128 * 64];
  __shared__ u16 VTs[2][64 * 128];
  const int tid = threadIdx.x;
  const int w = tid >> 6, l = tid & 63;
  const int lr = l & 15, lg = l >> 4;
  const int h = blockIdx.y, b = blockIdx.z;
  const int qtb = (b == 0) ? blockIdx.x : (15 - blockIdx.x);  // pair long+short per CU
  const int q0 = qtb * 128;
  const int wrow0 = q0 + 32 * w;
  const size_t kbase = ((size_t)(b * T_) * H_ + h) * DK_;
  const size_t vbase = (size_t)(b * H_ + h) * DK_ * (size_t)T_;

  auto STAGE = [&](int kt, int pb){
#pragma unroll
    for (int p = 0; p < 4; ++p){
      int kr0 = 32 * w + 8 * p;   // 8 K-rows per call (128B rows)
#ifdef HAS_GLLDS
      gl_lds16(K + kbase + (size_t)(kt * 128 + kr0 + (l >> 3)) * 1024 + (l & 7) * 8,
               &Ks[pb][kr0 * 64]);
#else
      *(uint4*)&Ks[pb][(kr0 + (l >> 3)) * 64 + (l & 7) * 8] =
          *(const uint4*)(K + kbase + (size_t)(kt * 128 + kr0 + (l >> 3)) * 1024 + (l & 7) * 8);
#endif
    }
#pragma unroll
    for (int p = 0; p < 4; ++p){
      int dr0 = 16 * w + 4 * p;   // 4 VT d-rows per call (256B rows)
#ifdef HAS_GLLDS
      gl_lds16(VT + vbase + (size_t)(dr0 + (l >> 4)) * T_ + kt * 128 + (l & 15) * 8,
               &VTs[pb][dr0 * 128]);
#else
      *(uint4*)&VTs[pb][(dr0 + (l >> 4)) * 128 + (l & 15) * 8] =
          *(const uint4*)(VT + vbase + (size_t)(dr0 + (l >> 4)) * T_ + kt * 128 + (l & 15) * 8);
#endif
    }
  };

  // Q fragments (pre-scaled): B-operand, rows wrow0+16mi+lr, d-slices s
  short8 qf[2][2];
#pragma unroll
  for (int mi = 0; mi < 2; ++mi)
#pragma unroll
    for (int s = 0; s < 2; ++s)
      qf[mi][s] = *(const short8*)(Q + kbase + (size_t)(wrow0 + 16 * mi + lr) * 1024 + s * 32 + 8 * lg);

  f32x4 acc[2][4] = {};
  float lsum[2] = {0.f, 0.f};
  const int ktend = qtb;

  STAGE(0, 0);
  __syncthreads();
  for (int kt = 0; kt <= ktend; ++kt){
    const int pb = kt & 1;
    if (kt < ktend) STAGE(kt + 1, pb ^ 1);
    const bool diag = (kt == ktend);   // only the final phase masks
    short8 pf[2][4];
#pragma unroll
    for (int jh = 0; jh < 2; ++jh){
      short8 kf[4][2];
#pragma unroll
      for (int j = 0; j < 4; ++j)
#pragma unroll
        for (int s = 0; s < 2; ++s)
          kf[j][s] = *(const short8*)&Ks[pb][((4 * jh + j) * 16 + lr) * 64 + (((4 * s + lg) ^ (lr & 7)) << 3)];
#pragma unroll
      for (int mi = 0; mi < 2; ++mi){
        f32x4 pr[4];
        float lacc = 0.f;
        const int lim = 32 * w + 16 * mi + lr;   // qrow - q0
#pragma unroll
        for (int j = 0; j < 4; ++j){
          const int j0 = 4 * jh + j;
          f32x4 z = {};
          z = __builtin_amdgcn_mfma_f32_16x16x32_bf16(kf[j][0], qf[mi][0], z, 0, 0, 0);
          z = __builtin_amdgcn_mfma_f32_16x16x32_bf16(kf[j][1], qf[mi][1], z, 0, 0, 0);
#pragma unroll
          for (int r = 0; r < 4; ++r){
            float e = EXP2(z[r]);
            if (diag && (16 * j0 + 4 * lg + r > lim)) e = 0.f;
            pr[j][r] = e;
            lacc += e;
          }
        }
        lsum[mi] += lacc;
        pf[mi][2 * jh]     = pack8(pr[0], pr[1]);
        pf[mi][2 * jh + 1] = pack8(pr[2], pr[3]);
      }
    }
    // PV: A = in-register P, B = V^T (matching perm slots, XOR-swizzled phys)
#pragma unroll
    for (int ks = 0; ks < 4; ++ks)
#pragma unroll
      for (int d0 = 0; d0 < 4; ++d0){
        short8 vf = *(const short8*)&VTs[pb][(d0 * 16 + lr) * 128 + (((4 * ks + lg) ^ (lr & 7)) << 3)];
        acc[0][d0] = __builtin_amdgcn_mfma_f32_16x16x32_bf16(pf[0][ks], vf, acc[0][d0], 0, 0, 0);
        acc[1][d0] = __builtin_amdgcn_mfma_f32_16x16x32_bf16(pf[1][ks], vf, acc[1][d0], 0, 0, 0);
      }
    __syncthreads();
  }

  // epilogue: reduce lsum across lg groups, redistribute to acc-row lanes, store
#pragma unroll
  for (int mi = 0; mi < 2; ++mi){
    float v = lsum[mi];
    v += __shfl_xor(v, 16);
    v += __shfl_xor(v, 32);
    float inv = 1.0f / v;     // valid for qrow = wrow0+16mi+lr at every lane
    float invr[4];
#pragma unroll
    for (int r = 0; r < 4; ++r) invr[r] = __shfl(inv, 4 * lg + r);  // provider lane 4lg+r
#pragma unroll
    for (int d0 = 0; d0 < 4; ++d0)
#pragma unroll
      for (int r = 0; r < 4; ++r){
        float ov = acc[mi][d0][r] * invr[r];
        O[kbase + (size_t)(wrow0 + 16 * mi + 4 * lg + r) * 1024 + d0 * 16 + lr] = f2bf(ov);
      }
  }
}

// ---------------- launcher ----------------
extern "C" void kernel_launch(void* const* d_in, const int* in_sizes, int n_in,
                              void* d_out, int out_size, void* d_ws, size_t ws_size,
                              hipStream_t stream)
{
  const float* x  = (const float*)d_in[0];
  const float* Wq = (const float*)d_in[2];
  const float* bq = (const float*)d_in[3];
  const float* Wk = (const float*)d_in[4];
  const float* bk = (const float*)d_in[5];
  const float* Wv = (const float*)d_in[6];
  const float* bv = (const float*)d_in[7];
  const float* Wo = (const float*)d_in[8];
  const float* bo = (const float*)d_in[9];

  char* ws = (char*)d_ws;
  u16* xb  = (u16*)(ws + 0);         // [0,8M)   x bf16; dead after QKV GEMM
  u16* wqb = (u16*)(ws + 8388608);
  u16* wkb = (u16*)(ws + 10485760);
  u16* wvb = (u16*)(ws + 12582912);
  u16* wob = (u16*)(ws + 14680064);
  u16* qb  = (u16*)(ws + 16777216);  // Q pre-scaled
  u16* kb  = (u16*)(ws + 25165824);  // K swizzled
  u16* vb  = (u16*)(ws + 33554432);  // V natural; dead after transpose
  u16* vtb = xb;                     // alias: V^T (128-chunk perm+XOR) after QKV GEMM
  u16* ab  = vb;                     // alias: attention output

  conv_all<<<8192, 256, 0, stream>>>(x, Wq, Wk, Wv, Wo, xb, wqb, wkb, wvb, wob);

  gemm_k5<1><<<dim3(24, 32), 256, 0, stream>>>(
      xb, wqb, wkb, wvb, bq, bk, bv, (void*)qb, (void*)kb, (void*)vb);

  transpose_v128<<<dim3(T_/128, H_, B_), 256, 0, stream>>>(vb, vtb);

  attn_v7<<<dim3(T_/128, H_, B_), 256, 0, stream>>>(qb, kb, vtb, ab);

  gemm_k5<0><<<dim3(8, 32), 256, 0, stream>>>(
      ab, wob, wob, wob, bo, bo, bo, d_out, d_out, d_out);
}